// Round 6
// baseline (729.322 us; speedup 1.0000x reference)
//
#include <hip/hip_runtime.h>
#include <stdint.h>

#define E 128
#define W 64
#define C 1024
#define S 8
#define NBUCK 4096

typedef unsigned long long u64;
typedef unsigned int u32;

__device__ __forceinline__ float sigm(float x) { return 1.0f / (1.0f + expf(-x)); }

// ---------------------------------------------------------------------------
// kInit: zero H,C; build xcat for step 0. grid = 1 x 1024.
// ---------------------------------------------------------------------------
__global__ __launch_bounds__(1024) void kInit(
    const float* __restrict__ ent_emb, const float* __restrict__ relation,
    const int* __restrict__ start_ent,
    float* __restrict__ Hst, float* __restrict__ Cst, float* __restrict__ xcatb)
{
  const int t = threadIdx.x;
  for (int i = t; i < W * E; i += 1024) { Hst[i] = 0.f; Cst[i] = 0.f; }
  const int w = t >> 4, q = t & 15;
  const int cur = start_ent[w];
  const float4* ep = (const float4*)(ent_emb + (size_t)cur * E);
  float4* xc = (float4*)(xcatb + (size_t)w * 384);
  xc[q * 2]     = ep[q * 2];
  xc[q * 2 + 1] = ep[q * 2 + 1];
  const float4 z4 = make_float4(0.f, 0.f, 0.f, 0.f);
  xc[32 + q * 2]     = z4;
  xc[32 + q * 2 + 1] = z4;
  const float4* rl = (const float4*)relation;
  xc[64 + q * 2]     = rl[q * 2];
  xc[64 + q * 2 + 1] = rl[q * 2 + 1];
}

// ---------------------------------------------------------------------------
// kZ: batched LSTM GEMM + gates. grid = 32 (16 unit-groups x 2 beam-halves),
//     block = 256 (32 beams x 8 units). Each thread: 4 gate-dots of len 384.
//     writes H, C, xcat[:,128:256].
// ---------------------------------------------------------------------------
__global__ __launch_bounds__(256) void kZ(
    const float* __restrict__ lstm_k, const float* __restrict__ lstm_r,
    const float* __restrict__ lstm_b,
    const float* __restrict__ xinb,   // [W][384] = [rel, ent, h_par]
    const float* __restrict__ cpb,    // [W][128] staged c_prev
    float* __restrict__ Hst, float* __restrict__ Cst, float* __restrict__ xcatb)
{
  const int b = blockIdx.x, t = threadIdx.x;
  const int ug = b >> 1, half = b & 1;
  const int u = (ug << 3) + (t & 7);
  const int wl = t >> 3, w = (half << 5) + wl;
  __shared__ __align__(16) float xin_l[32 * 384];

  for (int i = t; i < 32 * 384; i += 256)
    xin_l[i] = xinb[(size_t)(half << 5) * 384 + i];
  __syncthreads();

  const float4* xv4 = (const float4*)(xin_l + wl * 384);
  const int ji = u, jf = 128 + u, jg = 256 + u, jo = 384 + u;
  float zi = 0.f, zf = 0.f, zg = 0.f, zo = 0.f;
#pragma unroll 4
  for (int k4 = 0; k4 < 64; ++k4) {
    const float4 xv = xv4[k4];
    const float* K0 = lstm_k + (size_t)(k4 * 4) * 512;
    zi += xv.x * K0[ji] + xv.y * K0[512 + ji] + xv.z * K0[1024 + ji] + xv.w * K0[1536 + ji];
    zf += xv.x * K0[jf] + xv.y * K0[512 + jf] + xv.z * K0[1024 + jf] + xv.w * K0[1536 + jf];
    zg += xv.x * K0[jg] + xv.y * K0[512 + jg] + xv.z * K0[1024 + jg] + xv.w * K0[1536 + jg];
    zo += xv.x * K0[jo] + xv.y * K0[512 + jo] + xv.z * K0[1024 + jo] + xv.w * K0[1536 + jo];
  }
#pragma unroll 4
  for (int k4 = 0; k4 < 32; ++k4) {
    const float4 xv = xv4[64 + k4];
    const float* R0 = lstm_r + (size_t)(k4 * 4) * 512;
    zi += xv.x * R0[ji] + xv.y * R0[512 + ji] + xv.z * R0[1024 + ji] + xv.w * R0[1536 + ji];
    zf += xv.x * R0[jf] + xv.y * R0[512 + jf] + xv.z * R0[1024 + jf] + xv.w * R0[1536 + jf];
    zg += xv.x * R0[jg] + xv.y * R0[512 + jg] + xv.z * R0[1024 + jg] + xv.w * R0[1536 + jg];
    zo += xv.x * R0[jo] + xv.y * R0[512 + jo] + xv.z * R0[1024 + jo] + xv.w * R0[1536 + jo];
  }
  zi += lstm_b[ji]; zf += lstm_b[jf]; zg += lstm_b[jg]; zo += lstm_b[jo];
  const float cp = cpb[(size_t)w * E + u];
  const float cn = sigm(zf) * cp + sigm(zi) * tanhf(zg);
  const float hn = sigm(zo) * tanhf(cn);
  Hst[(size_t)w * E + u] = hn;
  Cst[(size_t)w * E + u] = cn;
  xcatb[(size_t)w * 384 + 128 + u] = hn;
}

// ---------------------------------------------------------------------------
// kM1: hmid = relu(xcat @ W1 + b1). grid = 96 (48 col-groups x 2 halves),
//      block = 256 (32 beams x 8 cols), 1 dot/thread.
// ---------------------------------------------------------------------------
__global__ __launch_bounds__(256) void kM1(
    const float* __restrict__ W1, const float* __restrict__ b1,
    const float* __restrict__ xcatb, float* __restrict__ hmidb)
{
  const int b = blockIdx.x, t = threadIdx.x;
  const int cg = b >> 1, half = b & 1;
  const int j = (cg << 3) + (t & 7);
  const int wl = t >> 3, w = (half << 5) + wl;
  __shared__ __align__(16) float x_l[32 * 384];
  for (int i = t; i < 32 * 384; i += 256)
    x_l[i] = xcatb[(size_t)(half << 5) * 384 + i];
  __syncthreads();
  const float4* xv4 = (const float4*)(x_l + wl * 384);
  float acc = 0.f;
#pragma unroll 4
  for (int k4 = 0; k4 < 96; ++k4) {
    const float4 xv = xv4[k4];
    const float* Wp = W1 + (size_t)(k4 * 4) * 384 + j;
    acc += xv.x * Wp[0] + xv.y * Wp[384] + xv.z * Wp[768] + xv.w * Wp[1152];
  }
  hmidb[(size_t)w * 384 + j] = fmaxf(acc + b1[j], 0.f);
}

// ---------------------------------------------------------------------------
// kM2: feat = relu(hmid @ W2 + b2). grid = 64 (32 col-groups x 2 halves).
// ---------------------------------------------------------------------------
__global__ __launch_bounds__(256) void kM2(
    const float* __restrict__ W2, const float* __restrict__ b2,
    const float* __restrict__ hmidb, float* __restrict__ featb)
{
  const int b = blockIdx.x, t = threadIdx.x;
  const int cg = b >> 1, half = b & 1;
  const int j = (cg << 3) + (t & 7);
  const int wl = t >> 3, w = (half << 5) + wl;
  __shared__ __align__(16) float x_l[32 * 384];
  for (int i = t; i < 32 * 384; i += 256)
    x_l[i] = hmidb[(size_t)(half << 5) * 384 + i];
  __syncthreads();
  const float4* xv4 = (const float4*)(x_l + wl * 384);
  float acc = 0.f;
#pragma unroll 4
  for (int k4 = 0; k4 < 96; ++k4) {
    const float4 xv = xv4[k4];
    const float* Wp = W2 + (size_t)(k4 * 4) * 256 + j;
    acc += xv.x * Wp[0] + xv.y * Wp[256] + xv.z * Wp[512] + xv.w * Wp[768];
  }
  featb[(size_t)w * 256 + j] = fmaxf(acc + b2[j], 0.f);
}

// ---------------------------------------------------------------------------
// kScore: gather-bound scoring, 4 threads/candidate. grid = 512 x 512.
// ---------------------------------------------------------------------------
__global__ __launch_bounds__(512) void kScore(
    int step,
    const float* __restrict__ ent_emb, const float* __restrict__ rel_emb,
    const int* __restrict__ cand_rel_ids, const int* __restrict__ cand_ent_ids,
    const float* __restrict__ featb, float* __restrict__ scoresb)
{
  const int b = blockIdx.x, tid = threadIdx.x;
  const int w = b >> 3, c0 = (b & 7) << 7;
  __shared__ __align__(16) float featl[256];
  __shared__ int srid[128], seid[128];

  const size_t idbase = (size_t)step * W * C + (size_t)w * C + c0;
  if (tid < 256) featl[tid] = featb[(size_t)w * 256 + tid];
  else if (tid < 384) srid[tid - 256] = cand_rel_ids[idbase + (tid - 256)];
  else seid[tid - 384] = cand_ent_ids[idbase + (tid - 384)];
  __syncthreads();

  const int cl = tid >> 2, j = tid & 3;
  const float4* rp = (const float4*)(rel_emb + (size_t)srid[cl] * E);
  const float4* ep = (const float4*)(ent_emb + (size_t)seid[cl] * E);
  const float4* f4 = (const float4*)featl;
  float ax = 0.f, ay = 0.f, az = 0.f, aw = 0.f;
#pragma unroll
  for (int i = 0; i < 8; ++i) {
    const float4 r = rp[j + 4 * i], f = f4[j + 4 * i];
    ax += r.x * f.x; ay += r.y * f.y; az += r.z * f.z; aw += r.w * f.w;
  }
#pragma unroll
  for (int i = 0; i < 8; ++i) {
    const float4 e = ep[j + 4 * i], f = f4[32 + j + 4 * i];
    ax += e.x * f.x; ay += e.y * f.y; az += e.z * f.z; aw += e.w * f.w;
  }
  float acc = (ax + ay) + (az + aw);
  acc += __shfl_xor(acc, 1, 64);
  acc += __shfl_xor(acc, 2, 64);
  if (j == 0) scoresb[(size_t)w * C + c0 + cl] = acc;
}

// ---------------------------------------------------------------------------
// kProb: softmax + probs write + per-row top-64. grid = 64 x 1024.
// ---------------------------------------------------------------------------
__global__ __launch_bounds__(1024) void kProb(
    int step, int last, const float* __restrict__ scoresb,
    float* __restrict__ out, u64* __restrict__ rowtop)
{
  const int w = blockIdx.x, tid = threadIdx.x;
  __shared__ float sred[32];
  __shared__ u32 hist[NBUCK];
  __shared__ u64 coll[C];
  __shared__ int s_cnt, s_B;

  const float score = scoresb[(size_t)w * C + tid];

  float v = score;
#pragma unroll
  for (int m = 32; m; m >>= 1) v = fmaxf(v, __shfl_xor(v, m, 64));
  if ((tid & 63) == 0) sred[tid >> 6] = v;
  __syncthreads();
  if (tid == 0) {
    float mm = sred[0];
#pragma unroll
    for (int i = 1; i < 16; ++i) mm = fmaxf(mm, sred[i]);
    sred[16] = mm;
  }
  __syncthreads();
  const float m = sred[16];
  const float pexp = expf(score - m);
  v = pexp;
#pragma unroll
  for (int mm2 = 32; mm2; mm2 >>= 1) v += __shfl_xor(v, mm2, 64);
  if ((tid & 63) == 0) sred[tid >> 6] = v;
  __syncthreads();
  if (tid == 0) {
    float ss = sred[0];
#pragma unroll
    for (int i = 1; i < 16; ++i) ss += sred[i];
    sred[17] = 1.f / ss;
  }
  __syncthreads();
  const float prob = pexp * sred[17];
  out[(size_t)step * W * C + (size_t)w * C + tid] = prob;
  if (last) return;

  for (int i = tid; i < NBUCK; i += 1024) hist[i] = 0;
  if (tid == 0) s_cnt = 0;
  __syncthreads();
  const u32 mono = __float_as_uint(prob) | 0x80000000u;
  const u64 key = ((u64)mono << 32) | (u32)~(u32)(w * C + tid);
  atomicAdd(&hist[(mono >> 19) & 0xFFFu], 1u);
  __syncthreads();
  for (int off = 1; off < NBUCK; off <<= 1) {
    u32 tmp[NBUCK / 1024];
    for (int i = tid, q = 0; i < NBUCK; i += 1024, ++q)
      tmp[q] = (i + off < NBUCK) ? hist[i + off] : 0u;
    __syncthreads();
    for (int i = tid, q = 0; i < NBUCK; i += 1024, ++q) hist[i] += tmp[q];
    __syncthreads();
  }
  for (int i = tid; i < NBUCK; i += 1024) {
    const u32 here = hist[i];
    const u32 nxt = (i + 1 < NBUCK) ? hist[i + 1] : 0u;
    if (here >= 64u && nxt < 64u) s_B = i;
  }
  __syncthreads();
  if ((int)((mono >> 19) & 0xFFFu) >= s_B) {
    const int q = atomicAdd(&s_cnt, 1);
    coll[q] = key;
  }
  __syncthreads();
  const int M = s_cnt;
  for (int i = tid; i < M; i += 1024) {
    const u64 ki = coll[i];
    int r = 0;
    for (int j = 0; j < M; ++j) r += (coll[j] > ki);
    if (r < 64) rowtop[(size_t)w * 64 + r] = ki;
  }
}

// ---------------------------------------------------------------------------
// kSel: global top-64 over row winners, then gather/stage next-step inputs:
//   xin = [rel_emb[rid], ent_emb[eid], H[par]], cpb = C[par],
//   xcat[:,0:128] = ent_emb[eid], xcat[:,256:384] = relation.
// grid = 1 x 1024.
// ---------------------------------------------------------------------------
__global__ __launch_bounds__(1024) void kSel(
    int step, const u64* __restrict__ rowtop,
    const int* __restrict__ cand_rel_ids, const int* __restrict__ cand_ent_ids,
    const float* __restrict__ ent_emb, const float* __restrict__ rel_emb,
    const float* __restrict__ relation,
    const float* __restrict__ Hst, const float* __restrict__ Cst,
    float* __restrict__ xinb, float* __restrict__ cpb, float* __restrict__ xcatb)
{
  const int tid = threadIdx.x;
  __shared__ u64 keys[W * 64];
  __shared__ u32 hist[NBUCK];
  __shared__ u64 coll[W * 64];
  __shared__ int s_cnt, s_B;
  __shared__ int s_par[W], s_rid[W], s_eid[W];

  for (int i = tid; i < W * 64; i += 1024) keys[i] = rowtop[i];
  for (int i = tid; i < NBUCK; i += 1024) hist[i] = 0;
  if (tid == 0) s_cnt = 0;
  __syncthreads();
  for (int i = tid; i < W * 64; i += 1024)
    atomicAdd(&hist[(u32)(keys[i] >> 51) & 0xFFFu], 1u);
  __syncthreads();
  for (int off = 1; off < NBUCK; off <<= 1) {
    u32 tmp[NBUCK / 1024];
    for (int i = tid, q = 0; i < NBUCK; i += 1024, ++q)
      tmp[q] = (i + off < NBUCK) ? hist[i + off] : 0u;
    __syncthreads();
    for (int i = tid, q = 0; i < NBUCK; i += 1024, ++q) hist[i] += tmp[q];
    __syncthreads();
  }
  for (int i = tid; i < NBUCK; i += 1024) {
    const u32 here = hist[i];
    const u32 nxt = (i + 1 < NBUCK) ? hist[i + 1] : 0u;
    if (here >= 64u && nxt < 64u) s_B = i;
  }
  __syncthreads();
  const int Bthr = s_B;
  for (int i = tid; i < W * 64; i += 1024) {
    const u64 key = keys[i];
    if ((int)((key >> 51) & 0xFFFull) >= Bthr) {
      const int q = atomicAdd(&s_cnt, 1);
      coll[q] = key;
    }
  }
  __syncthreads();
  const int M = s_cnt;
  for (int i = tid; i < M; i += 1024) {
    const u64 ki = coll[i];
    int r = 0;
    for (int j = 0; j < M; ++j) r += (coll[j] > ki);
    if (r < 64) {
      const u32 flat = ~(u32)(ki & 0xFFFFFFFFull);
      const int p = (int)(flat >> 10);
      const int sl = (int)(flat & 1023u);
      const size_t cbase = (size_t)step * W * C + (size_t)p * C + sl;
      s_par[r] = p;
      s_rid[r] = cand_rel_ids[cbase];
      s_eid[r] = cand_ent_ids[cbase];
    }
  }
  __syncthreads();

  // gather/stage: 16 threads per beam, 8 floats (2 float4) per thread-chunk
  const int w = tid >> 4, q = tid & 15;
  const int rid = s_rid[w], eid = s_eid[w], par = s_par[w];
  const float4* rp = (const float4*)(rel_emb + (size_t)rid * E);
  const float4* ep = (const float4*)(ent_emb + (size_t)eid * E);
  const float4* hp = (const float4*)(Hst + (size_t)par * E);
  const float4* cpp = (const float4*)(Cst + (size_t)par * E);
  const float4* rl = (const float4*)relation;
  float4* xi = (float4*)(xinb + (size_t)w * 384);
  float4* xc = (float4*)(xcatb + (size_t)w * 384);
  float4* cw = (float4*)(cpb + (size_t)w * E);
  const float4 e0 = ep[q * 2], e1 = ep[q * 2 + 1];
  xi[q * 2]          = rp[q * 2];
  xi[q * 2 + 1]      = rp[q * 2 + 1];
  xi[32 + q * 2]     = e0;
  xi[32 + q * 2 + 1] = e1;
  xi[64 + q * 2]     = hp[q * 2];
  xi[64 + q * 2 + 1] = hp[q * 2 + 1];
  xc[q * 2]          = e0;
  xc[q * 2 + 1]      = e1;
  xc[64 + q * 2]     = rl[q * 2];
  xc[64 + q * 2 + 1] = rl[q * 2 + 1];
  cw[q * 2]          = cpp[q * 2];
  cw[q * 2 + 1]      = cpp[q * 2 + 1];
}

// ---------------------------------------------------------------------------
extern "C" void kernel_launch(void* const* d_in, const int* in_sizes, int n_in,
                              void* d_out, int out_size, void* d_ws, size_t ws_size,
                              hipStream_t stream) {
  const float* ent_emb  = (const float*)d_in[0];
  const float* rel_emb  = (const float*)d_in[1];
  const float* relation = (const float*)d_in[2];
  const float* W1 = (const float*)d_in[3];
  const float* b1 = (const float*)d_in[4];
  const float* W2 = (const float*)d_in[5];
  const float* b2 = (const float*)d_in[6];
  const float* lstm_k = (const float*)d_in[7];
  const float* lstm_r = (const float*)d_in[8];
  const float* lstm_b = (const float*)d_in[9];
  const int* cr = (const int*)d_in[10];
  const int* ce = (const int*)d_in[11];
  const int* start_ent = (const int*)d_in[12];
  float* out = (float*)d_out;

  u64* rowtop = (u64*)d_ws;                                 // W*64 u64 (8B aligned)
  float* Hst   = (float*)(rowtop + (size_t)W * 64);         // W*E
  float* Cst   = Hst + (size_t)W * E;                       // W*E
  float* xinb  = Cst + (size_t)W * E;                       // W*384
  float* xcatb = xinb + (size_t)W * 384;                    // W*384
  float* hmidb = xcatb + (size_t)W * 384;                   // W*384
  float* featb = hmidb + (size_t)W * 384;                   // W*256
  float* cpb   = featb + (size_t)W * 256;                   // W*E
  float* scoresb = cpb + (size_t)W * E;                     // W*C

  kInit<<<1, 1024, 0, stream>>>(ent_emb, relation, start_ent, Hst, Cst, xcatb);
  for (int s = 0; s < S; ++s) {
    if (s > 0)
      kZ<<<32, 256, 0, stream>>>(lstm_k, lstm_r, lstm_b, xinb, cpb, Hst, Cst, xcatb);
    kM1<<<96, 256, 0, stream>>>(W1, b1, xcatb, hmidb);
    kM2<<<64, 256, 0, stream>>>(W2, b2, hmidb, featb);
    kScore<<<512, 512, 0, stream>>>(s, ent_emb, rel_emb, cr, ce, featb, scoresb);
    kProb<<<W, 1024, 0, stream>>>(s, (s == S - 1) ? 1 : 0, scoresb, out, rowtop);
    if (s < S - 1)
      kSel<<<1, 1024, 0, stream>>>(s, rowtop, cr, ce, ent_emb, rel_emb, relation,
                                   Hst, Cst, xinb, cpb, xcatb);
  }
}